// Round 6
// baseline (185.604 us; speedup 1.0000x reference)
//
#include <hip/hip_runtime.h>
#include <math.h>

namespace {

constexpr int LNUM = 2097152;        // L
constexpr int NROW = 5;              // N
constexpr int NSER = 10;             // rows total (0..4 rppg, 5..9 ppg)
constexpr int TPB = 256;
constexpr int CHUNK = 4096;          // elements per block
constexpr int CPR = LNUM / CHUNK;    // 512 chunks per row
constexpr int NBLK = NSER * CPR;     // 5120
constexpr int KIT = 4;               // iterations per wave (256 elems each)

struct Agg { int first; int last; int c; double s; };

__device__ __forceinline__ Agg combine(const Agg& a, const Agg& b) {
  // ordered segment-concat monoid: a LEFT, b RIGHT (non-commutative)
  Agg r;
  r.first = (a.first >= 0) ? a.first : b.first;
  r.last  = (b.last >= 0) ? b.last : a.last;
  r.s = a.s + b.s;
  r.c = a.c + b.c;
  if (a.last >= 0 && b.first >= 0) {
    r.s += 1.0 / (double)(b.first - a.last);
    r.c += 1;
  }
  return r;
}

__device__ __forceinline__ const float* row_ptr(const float* rppg,
                                                const float* ppg, int rw) {
  return (rw < NROW) ? rppg + (size_t)rw * LNUM
                     : ppg + (size_t)(rw - NROW) * LNUM;
}

// Lane owns 4 contiguous elements at p0 = seg + 4*lane (seg = wave-contiguous
// 256-elem segment start). Load = one fully-coalesced float4/lane (1KB/instr).
// Halo +-5 via shuffles; lanes 0/1/62/63 patch with guarded loads (-inf pad
// at row edges). Window-11 max via doubling. X[t] = x[p0+t];
// w[t] = max(x[p0+t-5 .. p0+t+5]).
__device__ __forceinline__ void window4(const float* __restrict__ x, int p0,
                                        float X[4], float w[4]) {
  const float4 f = *reinterpret_cast<const float4*>(x + p0);
  X[0] = f.x; X[1] = f.y; X[2] = f.z; X[3] = f.w;
  float Y[14];
  Y[5] = X[0]; Y[6] = X[1]; Y[7] = X[2]; Y[8] = X[3];
  Y[1] = __shfl_up(X[0], 1);  Y[2] = __shfl_up(X[1], 1);
  Y[3] = __shfl_up(X[2], 1);  Y[4] = __shfl_up(X[3], 1);
  Y[0] = __shfl_up(X[3], 2);
  Y[9] = __shfl_down(X[0], 1);  Y[10] = __shfl_down(X[1], 1);
  Y[11] = __shfl_down(X[2], 1); Y[12] = __shfl_down(X[3], 1);
  Y[13] = __shfl_down(X[0], 2);
  const int lane = threadIdx.x & 63;
  if (lane == 0) {
#pragma unroll
    for (int j = 0; j < 5; ++j) {
      int g = p0 - 5 + j;
      Y[j] = (g >= 0) ? x[g] : -INFINITY;
    }
  } else if (lane == 1) {
    int g = p0 - 5;
    Y[0] = (g >= 0) ? x[g] : -INFINITY;
  }
  if (lane == 63) {
#pragma unroll
    for (int j = 0; j < 5; ++j) {
      int g = p0 + 4 + j;
      Y[9 + j] = (g < LNUM) ? x[g] : -INFINITY;
    }
  } else if (lane == 62) {
    int g = p0 + 8;
    Y[13] = (g < LNUM) ? x[g] : -INFINITY;
  }
  float m2[13];
#pragma unroll
  for (int i = 0; i < 13; ++i) m2[i] = fmaxf(Y[i], Y[i + 1]);
  float m4[11];
#pragma unroll
  for (int i = 0; i < 11; ++i) m4[i] = fmaxf(m2[i], m2[i + 2]);
  float m8[7];
#pragma unroll
  for (int i = 0; i < 7; ++i) m8[i] = fmaxf(m4[i], m4[i + 4]);
#pragma unroll
  for (int t = 0; t < 4; ++t) w[t] = fmaxf(m8[t], m8[t + 3]);  // Y[t..t+10]
}

// Pass 1: per-chunk {sum, peak-value-sum, peak-count}. NO atomics.
// All accumulation in double (R3-proven arithmetic).
__global__ __launch_bounds__(TPB) void stats_kernel(
    const float* __restrict__ rppg, const float* __restrict__ ppg,
    double* __restrict__ psum, double* __restrict__ ppk,
    int* __restrict__ pnpk) {
  const int bid = blockIdx.x;
  const int rw = bid >> 9;          // /CPR
  const int chunk = bid & (CPR - 1);
  const float* x = row_ptr(rppg, ppg, rw);
  const int lane = threadIdx.x & 63;
  const int wid = threadIdx.x >> 6;
  const int segbase = chunk * CHUNK + wid * 1024;

  double tsum = 0.0, tpk = 0.0;
  int tn = 0;
  for (int k = 0; k < KIT; ++k) {
    const int p0 = segbase + k * 256 + 4 * lane;
    float X[4], w[4];
    window4(x, p0, X, w);
#pragma unroll
    for (int t = 0; t < 4; ++t) {
      tsum += (double)X[t];
      if (X[t] == w[t]) { tpk += (double)X[t]; ++tn; }
    }
  }
#pragma unroll
  for (int off = 32; off > 0; off >>= 1) {
    tsum += __shfl_down(tsum, off);
    tpk  += __shfl_down(tpk, off);
    tn   += __shfl_down(tn, off);
  }
  __shared__ double wsum[4], wpk[4];
  __shared__ int wn[4];
  if (lane == 0) { wsum[wid] = tsum; wpk[wid] = tpk; wn[wid] = tn; }
  __syncthreads();
  if (threadIdx.x == 0) {
    psum[bid] = wsum[0] + wsum[1] + wsum[2] + wsum[3];
    ppk[bid]  = wpk[0] + wpk[1] + wpk[2] + wpk[3];
    pnpk[bid] = wn[0] + wn[1] + wn[2] + wn[3];
  }
}

// Tiny: per-row raw-domain threshold from chunk partials.
// x_norm > mean_pk_norm/2  <=>  x > (mu + mean_pk_raw)/2  (affine, sd cancels)
__global__ __launch_bounds__(TPB) void thresh_kernel(
    const double* __restrict__ psum, const double* __restrict__ ppk,
    const int* __restrict__ pnpk, double* __restrict__ thr) {
  const int r = blockIdx.x;  // 0..9
  const int t = threadIdx.x;
  const int lane = t & 63;
  const int wid = t >> 6;
  double s0 = psum[r * CPR + t] + psum[r * CPR + t + 256];
  double p0 = ppk[r * CPR + t] + ppk[r * CPR + t + 256];
  int n0 = pnpk[r * CPR + t] + pnpk[r * CPR + t + 256];
#pragma unroll
  for (int off = 32; off > 0; off >>= 1) {
    s0 += __shfl_down(s0, off);
    p0 += __shfl_down(p0, off);
    n0 += __shfl_down(n0, off);
  }
  __shared__ double ws[4], wp[4];
  __shared__ int wn[4];
  if (lane == 0) { ws[wid] = s0; wp[wid] = p0; wn[wid] = n0; }
  __syncthreads();
  if (t == 0) {
    double S = ws[0] + ws[1] + ws[2] + ws[3];
    double P = wp[0] + wp[1] + wp[2] + wp[3];
    double Nn = (double)(wn[0] + wn[1] + wn[2] + wn[3]);
    thr[r] = 0.5 * (S / (double)LNUM + P / Nn);
  }
}

// Pass 2: per-chunk ordered gap aggregates via the R3-proven Agg/shfl-tree
// idiom (no ballot/clz). Per k-iteration: per-lane Agg over its 4 elems,
// 6-step ordered shfl tree, broadcast lane-0 result, fold into a uniform
// running wave Agg. NO atomics.
__global__ __launch_bounds__(TPB) void gap_kernel(
    const float* __restrict__ rppg, const float* __restrict__ ppg,
    const double* __restrict__ thr,
    int* __restrict__ cfirst, int* __restrict__ clast,
    double* __restrict__ csum, int* __restrict__ ccnt) {
  const int bid = blockIdx.x;
  const int rw = bid >> 9;
  const int chunk = bid & (CPR - 1);
  const float* x = row_ptr(rppg, ppg, rw);
  const float th = (float)thr[rw];
  const int lane = threadIdx.x & 63;
  const int wid = threadIdx.x >> 6;
  const int segbase = chunk * CHUNK + wid * 1024;

  Agg wacc; wacc.first = -1; wacc.last = -1; wacc.c = 0; wacc.s = 0.0;
  for (int k = 0; k < KIT; ++k) {
    const int p0 = segbase + k * 256 + 4 * lane;
    float X[4], w[4];
    window4(x, p0, X, w);
    Agg a; a.first = -1; a.last = -1; a.c = 0; a.s = 0.0;
#pragma unroll
    for (int t = 0; t < 4; ++t) {
      if (X[t] == w[t] && X[t] > th) {
        int p = p0 + t;
        if (a.last >= 0) { a.s += 1.0 / (double)(p - a.last); ++a.c; }
        else a.first = p;
        a.last = p;
      }
    }
    // ordered wave tree: lane i's segment is immediately left of lane i+off's
#pragma unroll
    for (int off = 1; off < 64; off <<= 1) {
      Agg b;
      b.first = __shfl_down(a.first, off);
      b.last  = __shfl_down(a.last, off);
      b.c     = __shfl_down(a.c, off);
      b.s     = __shfl_down(a.s, off);
      a = combine(a, b);
    }
    // broadcast lane 0's tree result; fold into uniform running wave Agg
    Agg t0;
    t0.first = __shfl(a.first, 0);
    t0.last  = __shfl(a.last, 0);
    t0.c     = __shfl(a.c, 0);
    t0.s     = __shfl(a.s, 0);
    wacc = combine(wacc, t0);
  }

  __shared__ Agg waggs[4];
  if (lane == 0) waggs[wid] = wacc;
  __syncthreads();
  if (threadIdx.x == 0) {
    Agg r = waggs[0];
    r = combine(r, waggs[1]);
    r = combine(r, waggs[2]);
    r = combine(r, waggs[3]);
    cfirst[bid] = r.first; clast[bid] = r.last;
    csum[bid] = r.s; ccnt[bid] = r.c;
  }
}

// Final: one block; per row combine the 512 chunk Aggs in order -> hr,
// then the score. (verbatim from the R3-proven version)
__global__ __launch_bounds__(TPB) void final_kernel(
    const int* __restrict__ cfirst, const int* __restrict__ clast,
    const double* __restrict__ csum, const int* __restrict__ ccnt,
    const int* __restrict__ fsp, float* __restrict__ out) {
  __shared__ Agg waggs[4];
  __shared__ double shr[NSER];
  const int t = threadIdx.x;
  const int lane = t & 63;
  const int wid = t >> 6;
  for (int r = 0; r < NSER; ++r) {
    const int i0 = r * CPR + 2 * t;
    Agg a0; a0.first = cfirst[i0];     a0.last = clast[i0];
    a0.c = ccnt[i0];                   a0.s = csum[i0];
    Agg a1; a1.first = cfirst[i0 + 1]; a1.last = clast[i0 + 1];
    a1.c = ccnt[i0 + 1];               a1.s = csum[i0 + 1];
    a0 = combine(a0, a1);
#pragma unroll
    for (int off = 1; off < 64; off <<= 1) {
      Agg b;
      b.first = __shfl_down(a0.first, off);
      b.last  = __shfl_down(a0.last, off);
      b.c     = __shfl_down(a0.c, off);
      b.s     = __shfl_down(a0.s, off);
      a0 = combine(a0, b);
    }
    if (lane == 0) waggs[wid] = a0;
    __syncthreads();
    if (t == 0) {
      Agg rr = waggs[0];
      rr = combine(rr, waggs[1]);
      rr = combine(rr, waggs[2]);
      rr = combine(rr, waggs[3]);
      shr[r] = 60.0 * (double)fsp[0] * rr.s / (double)rr.c;
    }
    __syncthreads();
  }
  if (t == 0) {
    double acc = 0.0;
    for (int r = 0; r < NROW; ++r)
      acc += fabs(shr[NROW + r] - shr[r]) / shr[NROW + r];
    out[0] = (float)(acc / (double)NROW);
  }
}

}  // namespace

extern "C" void kernel_launch(void* const* d_in, const int* in_sizes, int n_in,
                              void* d_out, int out_size, void* d_ws, size_t ws_size,
                              hipStream_t stream) {
  const float* rppg = (const float*)d_in[0];
  const float* ppg  = (const float*)d_in[1];
  const int* fsp    = (const int*)d_in[2];
  float* out        = (float*)d_out;
  char* ws          = (char*)d_ws;

  // ws layout (all naturally aligned)
  double* psum   = (double*)(ws);            // 5120*8 = 40960
  double* ppk    = (double*)(ws + 40960);    // 40960
  int*    pnpk   = (int*)(ws + 81920);       // 20480
  double* csum   = (double*)(ws + 102400);   // 40960
  int*    cfirst = (int*)(ws + 143360);      // 20480
  int*    clast  = (int*)(ws + 163840);      // 20480
  int*    ccnt   = (int*)(ws + 184320);      // 20480
  double* thr    = (double*)(ws + 204800);   // 80
  // total ~205 KB

  stats_kernel<<<NBLK, TPB, 0, stream>>>(rppg, ppg, psum, ppk, pnpk);
  thresh_kernel<<<NSER, TPB, 0, stream>>>(psum, ppk, pnpk, thr);
  gap_kernel<<<NBLK, TPB, 0, stream>>>(rppg, ppg, thr, cfirst, clast, csum, ccnt);
  final_kernel<<<1, TPB, 0, stream>>>(cfirst, clast, csum, ccnt, fsp, out);
  (void)in_sizes; (void)n_in; (void)out_size; (void)ws_size;
}

// Round 7
// 170.697 us; speedup vs baseline: 1.0873x; 1.0873x over previous
//
#include <hip/hip_runtime.h>
#include <math.h>
#include <limits.h>

namespace {

constexpr int LNUM = 2097152;        // L
constexpr int NROW = 5;              // N
constexpr int NSER = 10;             // rows total (0..4 rppg, 5..9 ppg)
constexpr int TPB = 256;
constexpr int CHUNK = 4096;          // elements per block
constexpr int CPR = LNUM / CHUNK;    // 512 chunks per row
constexpr int NBLK = NSER * CPR;     // 5120
constexpr int KIT = 4;               // iterations per wave (256 elems each)

struct Agg { int first; int last; int c; double s; };

__device__ __forceinline__ Agg combine(const Agg& a, const Agg& b) {
  // ordered segment-concat monoid: a LEFT, b RIGHT (non-commutative)
  Agg r;
  r.first = (a.first >= 0) ? a.first : b.first;
  r.last  = (b.last >= 0) ? b.last : a.last;
  r.s = a.s + b.s;
  r.c = a.c + b.c;
  if (a.last >= 0 && b.first >= 0) {
    r.s += 1.0 / (double)(b.first - a.last);
    r.c += 1;
  }
  return r;
}

__device__ __forceinline__ const float* row_ptr(const float* rppg,
                                                const float* ppg, int rw) {
  return (rw < NROW) ? rppg + (size_t)rw * LNUM
                     : ppg + (size_t)(rw - NROW) * LNUM;
}

// Lane owns 4 contiguous elements at p0 = seg + 4*lane (seg = wave-contiguous
// 256-elem segment start). Load = one fully-coalesced float4/lane (1KB/instr).
// Halo +-5 via shuffles; lanes 0/1/62/63 patch with guarded loads (-inf pad
// at row edges). Window-11 max via doubling. X[t] = x[p0+t];
// w[t] = max(x[p0+t-5 .. p0+t+5]).
__device__ __forceinline__ void window4(const float* __restrict__ x, int p0,
                                        float X[4], float w[4]) {
  const float4 f = *reinterpret_cast<const float4*>(x + p0);
  X[0] = f.x; X[1] = f.y; X[2] = f.z; X[3] = f.w;
  float Y[14];
  Y[5] = X[0]; Y[6] = X[1]; Y[7] = X[2]; Y[8] = X[3];
  Y[1] = __shfl_up(X[0], 1);  Y[2] = __shfl_up(X[1], 1);
  Y[3] = __shfl_up(X[2], 1);  Y[4] = __shfl_up(X[3], 1);
  Y[0] = __shfl_up(X[3], 2);
  Y[9] = __shfl_down(X[0], 1);  Y[10] = __shfl_down(X[1], 1);
  Y[11] = __shfl_down(X[2], 1); Y[12] = __shfl_down(X[3], 1);
  Y[13] = __shfl_down(X[0], 2);
  const int lane = threadIdx.x & 63;
  if (lane == 0) {
#pragma unroll
    for (int j = 0; j < 5; ++j) {
      int g = p0 - 5 + j;
      Y[j] = (g >= 0) ? x[g] : -INFINITY;
    }
  } else if (lane == 1) {
    int g = p0 - 5;
    Y[0] = (g >= 0) ? x[g] : -INFINITY;
  }
  if (lane == 63) {
#pragma unroll
    for (int j = 0; j < 5; ++j) {
      int g = p0 + 4 + j;
      Y[9 + j] = (g < LNUM) ? x[g] : -INFINITY;
    }
  } else if (lane == 62) {
    int g = p0 + 8;
    Y[13] = (g < LNUM) ? x[g] : -INFINITY;
  }
  float m2[13];
#pragma unroll
  for (int i = 0; i < 13; ++i) m2[i] = fmaxf(Y[i], Y[i + 1]);
  float m4[11];
#pragma unroll
  for (int i = 0; i < 11; ++i) m4[i] = fmaxf(m2[i], m2[i + 2]);
  float m8[7];
#pragma unroll
  for (int i = 0; i < 7; ++i) m8[i] = fmaxf(m4[i], m4[i + 4]);
#pragma unroll
  for (int t = 0; t < 4; ++t) w[t] = fmaxf(m8[t], m8[t + 3]);  // Y[t..t+10]
}

// Pass 1: per-chunk {sum, peak-value-sum, peak-count}. NO atomics.
// (verbatim from the R5-proven version)
__global__ __launch_bounds__(TPB) void stats_kernel(
    const float* __restrict__ rppg, const float* __restrict__ ppg,
    double* __restrict__ psum, double* __restrict__ ppk,
    int* __restrict__ pnpk) {
  const int bid = blockIdx.x;
  const int rw = bid >> 9;          // /CPR
  const int chunk = bid & (CPR - 1);
  const float* x = row_ptr(rppg, ppg, rw);
  const int lane = threadIdx.x & 63;
  const int wid = threadIdx.x >> 6;
  const int segbase = chunk * CHUNK + wid * 1024;

  double tsum = 0.0, tpk = 0.0;
  int tn = 0;
  for (int k = 0; k < KIT; ++k) {
    const int p0 = segbase + k * 256 + 4 * lane;
    float X[4], w[4];
    window4(x, p0, X, w);
#pragma unroll
    for (int t = 0; t < 4; ++t) {
      tsum += (double)X[t];
      if (X[t] == w[t]) { tpk += (double)X[t]; ++tn; }
    }
  }
#pragma unroll
  for (int off = 32; off > 0; off >>= 1) {
    tsum += __shfl_down(tsum, off);
    tpk  += __shfl_down(tpk, off);
    tn   += __shfl_down(tn, off);
  }
  __shared__ double wsum[4], wpk[4];
  __shared__ int wn[4];
  if (lane == 0) { wsum[wid] = tsum; wpk[wid] = tpk; wn[wid] = tn; }
  __syncthreads();
  if (threadIdx.x == 0) {
    psum[bid] = wsum[0] + wsum[1] + wsum[2] + wsum[3];
    ppk[bid]  = wpk[0] + wpk[1] + wpk[2] + wpk[3];
    pnpk[bid] = wn[0] + wn[1] + wn[2] + wn[3];
  }
}

// Tiny: per-row raw-domain threshold from chunk partials.
// x_norm > mean_pk_norm/2  <=>  x > (mu + mean_pk_raw)/2  (affine, sd cancels)
__global__ __launch_bounds__(TPB) void thresh_kernel(
    const double* __restrict__ psum, const double* __restrict__ ppk,
    const int* __restrict__ pnpk, double* __restrict__ thr) {
  const int r = blockIdx.x;  // 0..9
  const int t = threadIdx.x;
  const int lane = t & 63;
  const int wid = t >> 6;
  double s0 = psum[r * CPR + t] + psum[r * CPR + t + 256];
  double p0 = ppk[r * CPR + t] + ppk[r * CPR + t + 256];
  int n0 = pnpk[r * CPR + t] + pnpk[r * CPR + t + 256];
#pragma unroll
  for (int off = 32; off > 0; off >>= 1) {
    s0 += __shfl_down(s0, off);
    p0 += __shfl_down(p0, off);
    n0 += __shfl_down(n0, off);
  }
  __shared__ double ws[4], wp[4];
  __shared__ int wn[4];
  if (lane == 0) { ws[wid] = s0; wp[wid] = p0; wn[wid] = n0; }
  __syncthreads();
  if (t == 0) {
    double S = ws[0] + ws[1] + ws[2] + ws[3];
    double P = wp[0] + wp[1] + wp[2] + wp[3];
    double Nn = (double)(wn[0] + wn[1] + wn[2] + wn[3]);
    thr[r] = 0.5 * (S / (double)LNUM + P / Nn);
  }
}

// Pass 2: gap scan via shfl_up MAX-SCAN over peak positions.
// A lane's 4 elements hold at most ONE peak (peaks are width-11 window maxima
// => spacing >= 6), so per-lane state is one int. Positions increase with
// lane within a segment, so "previous peak" = max-scan of positions. Carry
// (wave-uniform) links the 4 segments. Gap reciprocal in f32 (matches
// reference dtype), accumulated in f64. All shuffles wave-uniform. NO atomics.
__global__ __launch_bounds__(TPB) void gap_kernel(
    const float* __restrict__ rppg, const float* __restrict__ ppg,
    const double* __restrict__ thr,
    int* __restrict__ cfirst, int* __restrict__ clast,
    double* __restrict__ csum, int* __restrict__ ccnt) {
  const int bid = blockIdx.x;
  const int rw = bid >> 9;
  const int chunk = bid & (CPR - 1);
  const float* x = row_ptr(rppg, ppg, rw);
  const float th = (float)thr[rw];
  const int lane = threadIdx.x & 63;
  const int wid = threadIdx.x >> 6;
  const int segbase = chunk * CHUNK + wid * 1024;

  double lsum = 0.0;
  int lcnt = 0;
  int lfirst = INT_MAX;   // per-lane earliest peak position (INT_MAX = none)
  int carry = -1;         // wave-uniform: last peak pos in segments so far
  for (int k = 0; k < KIT; ++k) {
    const int p0 = segbase + k * 256 + 4 * lane;
    float X[4], w[4];
    window4(x, p0, X, w);
    int pk = -1;  // at most one peak in this lane's 4 elements
#pragma unroll
    for (int t = 0; t < 4; ++t)
      if (X[t] == w[t] && X[t] > th) pk = p0 + t;
    if (pk >= 0 && lfirst == INT_MAX) lfirst = pk;
    // inclusive max-scan of peak positions across lanes
    int m = pk;
#pragma unroll
    for (int off = 1; off < 64; off <<= 1) {
      int u = __shfl_up(m, off);
      if (lane >= off) m = max(m, u);
    }
    int excl = __shfl_up(m, 1);                     // incl[lane-1] (lane>0)
    int prev = (lane == 0) ? carry : max(excl, carry);
    if (pk >= 0 && prev >= 0) {
      lsum += (double)(1.0f / (float)(pk - prev));
      ++lcnt;
    }
    int lastall = __shfl(m, 63);                    // max peak pos this segment
    carry = max(carry, lastall);
  }
  // wave reduction: sum lsum/lcnt, min lfirst
#pragma unroll
  for (int off = 32; off > 0; off >>= 1) {
    lsum += __shfl_down(lsum, off);
    lcnt += __shfl_down(lcnt, off);
    lfirst = min(lfirst, __shfl_down(lfirst, off));
  }
  __shared__ Agg waggs[4];
  if (lane == 0) {
    Agg a;
    a.first = (lfirst == INT_MAX) ? -1 : lfirst;
    a.last = carry;  // wave-uniform
    a.c = lcnt; a.s = lsum;
    waggs[wid] = a;
  }
  __syncthreads();
  if (threadIdx.x == 0) {
    Agg r = waggs[0];
    r = combine(r, waggs[1]);
    r = combine(r, waggs[2]);
    r = combine(r, waggs[3]);
    cfirst[bid] = r.first; clast[bid] = r.last;
    csum[bid] = r.s; ccnt[bid] = r.c;
  }
}

// Final: one block; per row combine the 512 chunk Aggs in order -> hr,
// then the score. (verbatim from the R5-proven version)
__global__ __launch_bounds__(TPB) void final_kernel(
    const int* __restrict__ cfirst, const int* __restrict__ clast,
    const double* __restrict__ csum, const int* __restrict__ ccnt,
    const int* __restrict__ fsp, float* __restrict__ out) {
  __shared__ Agg waggs[4];
  __shared__ double shr[NSER];
  const int t = threadIdx.x;
  const int lane = t & 63;
  const int wid = t >> 6;
  for (int r = 0; r < NSER; ++r) {
    const int i0 = r * CPR + 2 * t;
    Agg a0; a0.first = cfirst[i0];     a0.last = clast[i0];
    a0.c = ccnt[i0];                   a0.s = csum[i0];
    Agg a1; a1.first = cfirst[i0 + 1]; a1.last = clast[i0 + 1];
    a1.c = ccnt[i0 + 1];               a1.s = csum[i0 + 1];
    a0 = combine(a0, a1);
#pragma unroll
    for (int off = 1; off < 64; off <<= 1) {
      Agg b;
      b.first = __shfl_down(a0.first, off);
      b.last  = __shfl_down(a0.last, off);
      b.c     = __shfl_down(a0.c, off);
      b.s     = __shfl_down(a0.s, off);
      a0 = combine(a0, b);
    }
    if (lane == 0) waggs[wid] = a0;
    __syncthreads();
    if (t == 0) {
      Agg rr = waggs[0];
      rr = combine(rr, waggs[1]);
      rr = combine(rr, waggs[2]);
      rr = combine(rr, waggs[3]);
      shr[r] = 60.0 * (double)fsp[0] * rr.s / (double)rr.c;
    }
    __syncthreads();
  }
  if (t == 0) {
    double acc = 0.0;
    for (int r = 0; r < NROW; ++r)
      acc += fabs(shr[NROW + r] - shr[r]) / shr[NROW + r];
    out[0] = (float)(acc / (double)NROW);
  }
}

}  // namespace

extern "C" void kernel_launch(void* const* d_in, const int* in_sizes, int n_in,
                              void* d_out, int out_size, void* d_ws, size_t ws_size,
                              hipStream_t stream) {
  const float* rppg = (const float*)d_in[0];
  const float* ppg  = (const float*)d_in[1];
  const int* fsp    = (const int*)d_in[2];
  float* out        = (float*)d_out;
  char* ws          = (char*)d_ws;

  // ws layout (all naturally aligned)
  double* psum   = (double*)(ws);            // 5120*8 = 40960
  double* ppk    = (double*)(ws + 40960);    // 40960
  int*    pnpk   = (int*)(ws + 81920);       // 20480
  double* csum   = (double*)(ws + 102400);   // 40960
  int*    cfirst = (int*)(ws + 143360);      // 20480
  int*    clast  = (int*)(ws + 163840);      // 20480
  int*    ccnt   = (int*)(ws + 184320);      // 20480
  double* thr    = (double*)(ws + 204800);   // 80
  // total ~205 KB

  stats_kernel<<<NBLK, TPB, 0, stream>>>(rppg, ppg, psum, ppk, pnpk);
  thresh_kernel<<<NSER, TPB, 0, stream>>>(psum, ppk, pnpk, thr);
  gap_kernel<<<NBLK, TPB, 0, stream>>>(rppg, ppg, thr, cfirst, clast, csum, ccnt);
  final_kernel<<<1, TPB, 0, stream>>>(cfirst, clast, csum, ccnt, fsp, out);
  (void)in_sizes; (void)n_in; (void)out_size; (void)ws_size;
}